// Round 7
// baseline (84.812 us; speedup 1.0000x reference)
//
#include <hip/hip_runtime.h>
#include <hip/hip_cooperative_groups.h>

namespace cg = cooperative_groups;

// ---------------------------------------------------------------------------
// CFNO collapsed pipeline (3 dispatches):
//   (1) build_M:    M[16][256] (bf16) + c[16]; 64 blocks, table-indexed trig.
//   (2) patch_gemm: y = M @ patch + c via MFMA -> img bf16 [8][16][128][128]
//   (3) conv_bn:    COOPERATIVE. conv 3x3 from LDS-staged bf16 img, conv vals
//                   stay in registers; block psum/psq -> grid.sync() ->
//                   per-channel stats -> normalize from regs -> out.
// interp nearest 128->128 is the identity.
// Lessons: (r2) fence+same-line atomic across 8192 blocks = 230us serial.
//          (r4) patch_gemm at its 128MB-read floor.
//          (r5) build_M parallelization was the 10us.
//          (r6) uint4 = 8 bf16, NOT 16 — half-row LDS stage caused NaN.
// ---------------------------------------------------------------------------

typedef __bf16 bf16x8 __attribute__((ext_vector_type(8)));
typedef float f32x4 __attribute__((ext_vector_type(4)));

#define TWO_PI 6.283185307179586f

// workspace layout (bytes)
#define MB_OFF    0u        // __bf16 Mb[16*256]        (8 KB)
#define CB_OFF    8192u     // float cb[16]
#define PSUM_OFF  16384u    // float psum[1024]         (4 KB)
#define PSQ_OFF   20480u    // float psq[1024]          (4 KB)
#define IMG_OFF   24576u    // __bf16 img[8*16*128*128] (4 MB)

// ---------------- kernel 1: build M (bf16) and bias c ----------------------
__global__ __launch_bounds__(256) void build_M(
    const float* __restrict__ Wr, const float* __restrict__ br,
    const float* __restrict__ Wi, const float* __restrict__ bi,
    __bf16* __restrict__ Mb, float* __restrict__ cb) {
  __shared__ float costab[256], sintab[256];
  __shared__ float A2[512];       // interleaved (Ar, Ai)
  __shared__ float part[4][64];
  const int bx = blockIdx.x;
  const int n = bx >> 2;
  const int mq = bx & 3;
  const int t = threadIdx.x;

  float sv, cv;
  sincosf((float)t * (TWO_PI / 256.0f), &sv, &cv);
  costab[t] = cv;
  sintab[t] = sv;
  __syncthreads();

  // phase 1: A[n][k] = (1/16) sum_d (Wr+iWi)[d][k] * e^{+2*pi*i*n*d/16}, k = t
  {
    float ar = 0.f, ai = 0.f;
#pragma unroll
    for (int d = 0; d < 16; ++d) {
      int tt = ((n * d) & 15) * 16;
      float cp = costab[tt], sp = sintab[tt];
      float wr = Wr[d * 256 + t], wi = Wi[d * 256 + t];
      ar += wr * cp - wi * sp;
      ai += wr * sp + wi * cp;
    }
    A2[2 * t]     = ar * (1.0f / 16.0f);
    A2[2 * t + 1] = ai * (1.0f / 16.0f);
  }
  if (mq == 0 && t == 0) {
    float s = 0.f;
    for (int d = 0; d < 16; ++d) {
      int tt = ((n * d) & 15) * 16;
      s += (br[d] - bi[d]) * costab[tt] - (br[d] + bi[d]) * sintab[tt];
    }
    cb[n] = s * (1.0f / 16.0f);
  }
  __syncthreads();

  // phase 2: M[n][m] = sum_k Ar[k]*costab[(k*m)&255] + Ai[k]*sintab[(k*m)&255]
  const int m = mq * 64 + (t & 63);
  const int k0 = (t >> 6) * 64;
  float acc = 0.f;
#pragma unroll 4
  for (int kk = 0; kk < 64; ++kk) {
    const int k = k0 + kk;
    const int idx = (k * m) & 255;
    acc += A2[2 * k] * costab[idx] + A2[2 * k + 1] * sintab[idx];
  }
  part[t >> 6][t & 63] = acc;
  __syncthreads();
  if (t < 64) {
    const float r = part[0][t] + part[1][t] + part[2][t] + part[3][t];
    Mb[n * 256 + mq * 64 + t] = (__bf16)r;
  }
}

// ---------------- kernel 2: patch GEMM via MFMA -> bf16 img ----------------
__global__ __launch_bounds__(256) void patch_gemm(
    const float* __restrict__ x, const __bf16* __restrict__ Mb,
    const float* __restrict__ cb, __bf16* __restrict__ img) {
  const int t = threadIdx.x;
  const int l = t & 63;
  const int wv = t >> 6;
  const int tile = blockIdx.x * 4 + wv;  // 0..8191
  const int b = tile >> 10;              // 0..7
  const int ph = (tile >> 3) & 127;      // patch row
  const int pwb = (tile & 7) * 16;       // patch col base
  const int q = l & 15;                  // A: row d ; B: col patch
  const int g = l >> 4;                  // k-group 0..3

  bf16x8 mfrag[8];
#pragma unroll
  for (int kb = 0; kb < 8; ++kb) {
    mfrag[kb] = *(const bf16x8*)(Mb + q * 256 + kb * 32 + g * 8);
  }
  const float4 cv4 = ((const float4*)cb)[g];
  f32x4 acc = {cv4.x, cv4.y, cv4.z, cv4.w};

  const float* xbase = x + (size_t)b * 4194304 + (size_t)(ph * 16) * 2048 +
                       (size_t)(pwb + q) * 16 + (g & 1) * 8;
#pragma unroll
  for (int kb = 0; kb < 8; ++kb) {
    const int s1 = kb * 2 + (g >> 1);
    const float* xp = xbase + s1 * 2048;
    const float4 v0 = *(const float4*)xp;
    const float4 v1 = *(const float4*)(xp + 4);
    bf16x8 p;
    p[0] = (__bf16)v0.x; p[1] = (__bf16)v0.y; p[2] = (__bf16)v0.z; p[3] = (__bf16)v0.w;
    p[4] = (__bf16)v1.x; p[5] = (__bf16)v1.y; p[6] = (__bf16)v1.z; p[7] = (__bf16)v1.w;
    acc = __builtin_amdgcn_mfma_f32_16x16x32_bf16(mfrag[kb], p, acc, 0, 0, 0);
  }

#pragma unroll
  for (int r = 0; r < 4; ++r) {
    const int d = g * 4 + r;
    img[(((size_t)b * 16 + d) * 128 + ph) * 128 + pwb + q] = (__bf16)acc[r];
  }
}

// ---------------- kernel 3: cooperative conv + BN + write ------------------
// grid 1024 x 256 (= 4 blocks/CU on 256 CUs, co-resident).
// bx -> plane p = bx>>3 (b = p>>4, d = p&15), band = bx&7 (16 rows).
// LDS: 18 rows x 144 cols bf16 (8-col zero pads both sides, 16B aligned).
__global__ __launch_bounds__(256, 4) void conv_bn(
    const __bf16* __restrict__ img, const float* __restrict__ cw,
    const float* __restrict__ cbias, const float* __restrict__ gamma,
    const float* __restrict__ beta, float* __restrict__ psum,
    float* __restrict__ psq, float* __restrict__ out) {
  __shared__ alignas(16) __bf16 slds[18][144];
  __shared__ float r1[4], r2[4];
  __shared__ float sc_sh, sh_sh;

  const int bx = blockIdx.x;
  const int p = bx >> 3;        // (b,d) plane 0..127
  const int d = p & 15;
  const int band = bx & 7;      // 16-row band
  const int t = threadIdx.x;
  const int row0 = band * 16;

  // ---- stage img band (+1 halo row each side) into LDS, zero-padded ----
  // 18 rows x 8 chunks of 16 bf16 (32 B = TWO uint4) per thread. [r6 fix]
  if (t < 144) {
    const int s = t >> 3;
    const int ch = t & 7;
    const int gr = row0 - 1 + s;
    uint4 v0 = {0u, 0u, 0u, 0u}, v1 = {0u, 0u, 0u, 0u};
    if (gr >= 0 && gr <= 127) {
      const uint4* src =
          (const uint4*)(img + (size_t)p * 16384 + gr * 128 + ch * 16);
      v0 = src[0];
      v1 = src[1];
    }
    *(uint4*)&slds[s][8 + ch * 16] = v0;
    *(uint4*)&slds[s][8 + ch * 16 + 8] = v1;
  }
  if (t < 18) {                 // zero col pads (8 bf16 each side)
    uint4 z = {0u, 0u, 0u, 0u};
    *(uint4*)&slds[t][0] = z;
    *(uint4*)&slds[t][136] = z;
  }
  __syncthreads();

  // ---- conv 3x3: 8 pixels per thread, values stay in registers ----
  float w[9];
#pragma unroll
  for (int q = 0; q < 9; ++q) w[q] = cw[d * 9 + q];
  const float bias = cbias[d];
  const int j = t & 127;        // col
  const int r0 = t >> 7;        // row parity

  float vals[8];
  float s1 = 0.f, s2 = 0.f;
#pragma unroll
  for (int k = 0; k < 8; ++k) {
    const int r = r0 + 2 * k;   // local row 0..15; lds row index = r..r+2
    float acc = bias;
#pragma unroll
    for (int u = 0; u < 3; ++u) {
#pragma unroll
      for (int v = 0; v < 3; ++v) {
        acc += w[u * 3 + v] * (float)slds[r + u][7 + j + v];
      }
    }
    vals[k] = acc;
    s1 += acc;
    s2 += acc * acc;
  }

  // ---- block partial stats ----
#pragma unroll
  for (int off = 32; off > 0; off >>= 1) {
    s1 += __shfl_down(s1, off, 64);
    s2 += __shfl_down(s2, off, 64);
  }
  if ((t & 63) == 0) { r1[t >> 6] = s1; r2[t >> 6] = s2; }
  __syncthreads();
  if (t == 0) {
    psum[bx] = r1[0] + r1[1] + r1[2] + r1[3];
    psq[bx]  = r2[0] + r2[1] + r2[2] + r2[3];
  }

  // ---- grid-wide barrier, then per-channel finalize (redundant per block) --
  cg::this_grid().sync();

  if (t < 64) {                 // 64 partials for this block's channel d
    const int bb = t >> 3;      // batch 0..7
    const int bd = t & 7;       // band 0..7
    const int src = bb * 128 + d * 8 + bd;
    float a1 = psum[src];
    float a2 = psq[src];
#pragma unroll
    for (int off = 32; off > 0; off >>= 1) {
      a1 += __shfl_down(a1, off, 64);
      a2 += __shfl_down(a2, off, 64);
    }
    if (t == 0) {
      const float invN = 1.0f / 131072.0f;
      const float mean = a1 * invN;
      const float var = a2 * invN - mean * mean;
      const float sc = gamma[d] * rsqrtf(var + 1e-5f);
      sc_sh = sc;
      sh_sh = beta[d] - mean * sc;
    }
  }
  __syncthreads();

  const float sc = sc_sh, sh = sh_sh;
#pragma unroll
  for (int k = 0; k < 8; ++k) {
    const int gr = row0 + r0 + 2 * k;
    out[(size_t)p * 16384 + gr * 128 + j] = vals[k] * sc + sh;
  }
}

// ---------------- launcher --------------------------------------------------
extern "C" void kernel_launch(void* const* d_in, const int* in_sizes, int n_in,
                              void* d_out, int out_size, void* d_ws,
                              size_t ws_size, hipStream_t stream) {
  const float* x     = (const float*)d_in[0];
  const float* Wr    = (const float*)d_in[1];
  const float* br    = (const float*)d_in[2];
  const float* Wi    = (const float*)d_in[3];
  const float* bi    = (const float*)d_in[4];
  const float* cw    = (const float*)d_in[5];
  const float* cbias = (const float*)d_in[6];
  const float* gamma = (const float*)d_in[7];
  const float* beta  = (const float*)d_in[8];
  float* out = (float*)d_out;

  char* w = (char*)d_ws;
  __bf16* Mb   = (__bf16*)(w + MB_OFF);
  float* cb    = (float*)(w + CB_OFF);
  float* psum  = (float*)(w + PSUM_OFF);
  float* psq   = (float*)(w + PSQ_OFF);
  __bf16* img  = (__bf16*)(w + IMG_OFF);

  build_M<<<64, 256, 0, stream>>>(Wr, br, Wi, bi, Mb, cb);
  patch_gemm<<<2048, 256, 0, stream>>>(x, Mb, cb, img);

  void* args[] = {(void*)&img, (void*)&cw, (void*)&cbias, (void*)&gamma,
                  (void*)&beta, (void*)&psum, (void*)&psq, (void*)&out};
  hipLaunchCooperativeKernel((void*)conv_bn, dim3(1024), dim3(256), args, 0,
                             stream);
}

// Round 8
// 39.466 us; speedup vs baseline: 2.1490x; 2.1490x over previous
//
#include <hip/hip_runtime.h>

// ---------------------------------------------------------------------------
// CFNO collapsed pipeline (4 dispatches, atomic-free, no grid.sync):
//   (1) build_M:    M[16][256] (bf16) + c[16]; 64 blocks, table-indexed trig.
//   (2) patch_gemm: y = M @ patch + c via MFMA -> img bf16 [8][16][128][128]
//   (3) conv_stats: LDS-staged 3x3 depthwise conv -> convbuf f32 + psum/psq
//   (4) affine:     per-block redundant finalize (64 partials) + normalize
// interp nearest 128->128 is the identity.
// Lessons: (r2) fence+same-line atomic across 8192 blocks = 230us serial.
//          (r4) patch_gemm at its 128MB-read floor.
//          (r5) build_M parallelization was the 10us.
//          (r6) uint4 = 8 bf16, NOT 16 — half-row LDS stage caused NaN.
//          (r7) cooperative grid.sync() costs ~30us — never worth <30us of
//               traffic. bf16 img + LDS conv validated (absmax 0.03125).
// ---------------------------------------------------------------------------

typedef __bf16 bf16x8 __attribute__((ext_vector_type(8)));
typedef float f32x4 __attribute__((ext_vector_type(4)));

#define TWO_PI 6.283185307179586f

// workspace layout (bytes)
#define MB_OFF    0u        // __bf16 Mb[16*256]        (8 KB)
#define CB_OFF    8192u     // float cb[16]
#define PSUM_OFF  16384u    // float psum[1024]         (4 KB)
#define PSQ_OFF   20480u    // float psq[1024]          (4 KB)
#define IMG_OFF   24576u    // __bf16 img[8*16*128*128] (4 MB)
#define CONV_OFF  4218880u  // float convbuf[8*16*128*128] (8 MB)

// ---------------- kernel 1: build M (bf16) and bias c ----------------------
__global__ __launch_bounds__(256) void build_M(
    const float* __restrict__ Wr, const float* __restrict__ br,
    const float* __restrict__ Wi, const float* __restrict__ bi,
    __bf16* __restrict__ Mb, float* __restrict__ cb) {
  __shared__ float costab[256], sintab[256];
  __shared__ float A2[512];       // interleaved (Ar, Ai)
  __shared__ float part[4][64];
  const int bx = blockIdx.x;
  const int n = bx >> 2;
  const int mq = bx & 3;
  const int t = threadIdx.x;

  float sv, cv;
  sincosf((float)t * (TWO_PI / 256.0f), &sv, &cv);
  costab[t] = cv;
  sintab[t] = sv;
  __syncthreads();

  // phase 1: A[n][k] = (1/16) sum_d (Wr+iWi)[d][k] * e^{+2*pi*i*n*d/16}, k = t
  {
    float ar = 0.f, ai = 0.f;
#pragma unroll
    for (int d = 0; d < 16; ++d) {
      int tt = ((n * d) & 15) * 16;
      float cp = costab[tt], sp = sintab[tt];
      float wr = Wr[d * 256 + t], wi = Wi[d * 256 + t];
      ar += wr * cp - wi * sp;
      ai += wr * sp + wi * cp;
    }
    A2[2 * t]     = ar * (1.0f / 16.0f);
    A2[2 * t + 1] = ai * (1.0f / 16.0f);
  }
  if (mq == 0 && t == 0) {
    float s = 0.f;
    for (int d = 0; d < 16; ++d) {
      int tt = ((n * d) & 15) * 16;
      s += (br[d] - bi[d]) * costab[tt] - (br[d] + bi[d]) * sintab[tt];
    }
    cb[n] = s * (1.0f / 16.0f);
  }
  __syncthreads();

  // phase 2: M[n][m] = sum_k Ar[k]*costab[(k*m)&255] + Ai[k]*sintab[(k*m)&255]
  const int m = mq * 64 + (t & 63);
  const int k0 = (t >> 6) * 64;
  float acc = 0.f;
#pragma unroll 4
  for (int kk = 0; kk < 64; ++kk) {
    const int k = k0 + kk;
    const int idx = (k * m) & 255;
    acc += A2[2 * k] * costab[idx] + A2[2 * k + 1] * sintab[idx];
  }
  part[t >> 6][t & 63] = acc;
  __syncthreads();
  if (t < 64) {
    const float r = part[0][t] + part[1][t] + part[2][t] + part[3][t];
    Mb[n * 256 + mq * 64 + t] = (__bf16)r;
  }
}

// ---------------- kernel 2: patch GEMM via MFMA -> bf16 img ----------------
__global__ __launch_bounds__(256) void patch_gemm(
    const float* __restrict__ x, const __bf16* __restrict__ Mb,
    const float* __restrict__ cb, __bf16* __restrict__ img) {
  const int t = threadIdx.x;
  const int l = t & 63;
  const int wv = t >> 6;
  const int tile = blockIdx.x * 4 + wv;  // 0..8191
  const int b = tile >> 10;              // 0..7
  const int ph = (tile >> 3) & 127;      // patch row
  const int pwb = (tile & 7) * 16;       // patch col base
  const int q = l & 15;                  // A: row d ; B: col patch
  const int g = l >> 4;                  // k-group 0..3

  bf16x8 mfrag[8];
#pragma unroll
  for (int kb = 0; kb < 8; ++kb) {
    mfrag[kb] = *(const bf16x8*)(Mb + q * 256 + kb * 32 + g * 8);
  }
  const float4 cv4 = ((const float4*)cb)[g];
  f32x4 acc = {cv4.x, cv4.y, cv4.z, cv4.w};

  const float* xbase = x + (size_t)b * 4194304 + (size_t)(ph * 16) * 2048 +
                       (size_t)(pwb + q) * 16 + (g & 1) * 8;
#pragma unroll
  for (int kb = 0; kb < 8; ++kb) {
    const int s1 = kb * 2 + (g >> 1);
    const float* xp = xbase + s1 * 2048;
    const float4 v0 = *(const float4*)xp;
    const float4 v1 = *(const float4*)(xp + 4);
    bf16x8 p;
    p[0] = (__bf16)v0.x; p[1] = (__bf16)v0.y; p[2] = (__bf16)v0.z; p[3] = (__bf16)v0.w;
    p[4] = (__bf16)v1.x; p[5] = (__bf16)v1.y; p[6] = (__bf16)v1.z; p[7] = (__bf16)v1.w;
    acc = __builtin_amdgcn_mfma_f32_16x16x32_bf16(mfrag[kb], p, acc, 0, 0, 0);
  }

#pragma unroll
  for (int r = 0; r < 4; ++r) {
    const int d = g * 4 + r;
    img[(((size_t)b * 16 + d) * 128 + ph) * 128 + pwb + q] = (__bf16)acc[r];
  }
}

// ---------------- kernel 3: LDS-staged conv -> convbuf + partial stats -----
// grid 1024: bx -> plane p = bx>>3 (b = p>>4, d = p&15), band = bx&7 (16 rows)
// LDS: 18 rows x 144 cols bf16, 8-col zero pads both sides.
__global__ __launch_bounds__(256) void conv_stats(
    const __bf16* __restrict__ img, const float* __restrict__ cw,
    const float* __restrict__ cbias, float* __restrict__ convbuf,
    float* __restrict__ psum, float* __restrict__ psq) {
  __shared__ alignas(16) __bf16 slds[18][144];
  __shared__ float r1[4], r2[4];

  const int bx = blockIdx.x;
  const int p = bx >> 3;        // (b,d) plane 0..127
  const int d = p & 15;
  const int band = bx & 7;
  const int t = threadIdx.x;
  const int row0 = band * 16;

  // stage band (+1 halo row each side); 32B = two uint4 per thread [r6 fix]
  if (t < 144) {
    const int s = t >> 3;
    const int ch = t & 7;
    const int gr = row0 - 1 + s;
    uint4 v0 = {0u, 0u, 0u, 0u}, v1 = {0u, 0u, 0u, 0u};
    if (gr >= 0 && gr <= 127) {
      const uint4* src =
          (const uint4*)(img + (size_t)p * 16384 + gr * 128 + ch * 16);
      v0 = src[0];
      v1 = src[1];
    }
    *(uint4*)&slds[s][8 + ch * 16] = v0;
    *(uint4*)&slds[s][8 + ch * 16 + 8] = v1;
  }
  if (t < 18) {
    uint4 z = {0u, 0u, 0u, 0u};
    *(uint4*)&slds[t][0] = z;
    *(uint4*)&slds[t][136] = z;
  }
  __syncthreads();

  float w[9];
#pragma unroll
  for (int q = 0; q < 9; ++q) w[q] = cw[d * 9 + q];
  const float bias = cbias[d];
  const int j = t & 127;        // col
  const int r0 = t >> 7;        // row parity

  float s1 = 0.f, s2 = 0.f;
#pragma unroll
  for (int k = 0; k < 8; ++k) {
    const int r = r0 + 2 * k;   // local row 0..15
    float acc = bias;
#pragma unroll
    for (int u = 0; u < 3; ++u) {
#pragma unroll
      for (int v = 0; v < 3; ++v) {
        acc += w[u * 3 + v] * (float)slds[r + u][7 + j + v];
      }
    }
    convbuf[(size_t)p * 16384 + (row0 + r) * 128 + j] = acc;
    s1 += acc;
    s2 += acc * acc;
  }

#pragma unroll
  for (int off = 32; off > 0; off >>= 1) {
    s1 += __shfl_down(s1, off, 64);
    s2 += __shfl_down(s2, off, 64);
  }
  if ((t & 63) == 0) { r1[t >> 6] = s1; r2[t >> 6] = s2; }
  __syncthreads();
  if (t == 0) {
    psum[bx] = r1[0] + r1[1] + r1[2] + r1[3];
    psq[bx]  = r2[0] + r2[1] + r2[2] + r2[3];
  }
}

// ---------------- kernel 4: per-block finalize + affine stream -------------
// grid 2048: block = 256 float4 = 1024 consecutive floats -> single (b,d);
// d = (bx>>4)&15. Redundant 64-partial reduce per block (L2-served, 4KB).
__global__ __launch_bounds__(256) void affine(
    const float4* __restrict__ convbuf, const float* __restrict__ psum,
    const float* __restrict__ psq, const float* __restrict__ gamma,
    const float* __restrict__ beta, float4* __restrict__ out) {
  __shared__ float sc_sh, sh_sh;
  const int t = threadIdx.x;
  const int i = blockIdx.x * 256 + t;   // float4 index, 0..524287
  const int d = (blockIdx.x >> 4) & 15;

  const float4 v = convbuf[i];          // issue load early

  if (t < 64) {                         // 64 partials for channel d
    const int bb = t >> 3;              // batch 0..7
    const int bd = t & 7;               // band 0..7
    float a1 = psum[bb * 128 + d * 8 + bd];
    float a2 = psq [bb * 128 + d * 8 + bd];
#pragma unroll
    for (int off = 32; off > 0; off >>= 1) {
      a1 += __shfl_down(a1, off, 64);
      a2 += __shfl_down(a2, off, 64);
    }
    if (t == 0) {
      const float invN = 1.0f / 131072.0f;
      const float mean = a1 * invN;
      const float var = a2 * invN - mean * mean;
      const float sc = gamma[d] * rsqrtf(var + 1e-5f);
      sc_sh = sc;
      sh_sh = beta[d] - mean * sc;
    }
  }
  __syncthreads();

  const float sc = sc_sh, sh = sh_sh;
  float4 o;
  o.x = v.x * sc + sh; o.y = v.y * sc + sh;
  o.z = v.z * sc + sh; o.w = v.w * sc + sh;
  out[i] = o;
}

// ---------------- launcher --------------------------------------------------
extern "C" void kernel_launch(void* const* d_in, const int* in_sizes, int n_in,
                              void* d_out, int out_size, void* d_ws,
                              size_t ws_size, hipStream_t stream) {
  const float* x     = (const float*)d_in[0];
  const float* Wr    = (const float*)d_in[1];
  const float* br    = (const float*)d_in[2];
  const float* Wi    = (const float*)d_in[3];
  const float* bi    = (const float*)d_in[4];
  const float* cw    = (const float*)d_in[5];
  const float* cbias = (const float*)d_in[6];
  const float* gamma = (const float*)d_in[7];
  const float* beta  = (const float*)d_in[8];
  float* out = (float*)d_out;

  char* w = (char*)d_ws;
  __bf16* Mb    = (__bf16*)(w + MB_OFF);
  float* cb     = (float*)(w + CB_OFF);
  float* psum   = (float*)(w + PSUM_OFF);
  float* psq    = (float*)(w + PSQ_OFF);
  __bf16* img   = (__bf16*)(w + IMG_OFF);
  float* convbuf= (float*)(w + CONV_OFF);

  build_M<<<64, 256, 0, stream>>>(Wr, br, Wi, bi, Mb, cb);
  patch_gemm<<<2048, 256, 0, stream>>>(x, Mb, cb, img);
  conv_stats<<<1024, 256, 0, stream>>>(img, cw, cbias, convbuf, psum, psq);
  affine<<<2048, 256, 0, stream>>>((const float4*)convbuf, psum, psq,
                                   gamma, beta, (float4*)out);
}

// Round 9
// 37.957 us; speedup vs baseline: 2.2344x; 1.0398x over previous
//
#include <hip/hip_runtime.h>

// ---------------------------------------------------------------------------
// CFNO collapsed pipeline (4 dispatches, atomic-free, no grid.sync):
//   (1) build_M:    M[16][256] (bf16) + c[16]; 64 blocks, table-indexed trig.
//   (2) patch_gemm: y = M @ patch + c via MFMA -> img bf16 [8][16][128][128]
//   (3) conv_stats: LDS-staged 3x3 depthwise conv, STATS ONLY -> psum/psq
//   (4) conv_norm:  finalize scale/shift per block + recompute conv + write
// interp nearest 128->128 is the identity. No convbuf: conv is recomputed
// (cheaper than an 8MB f32 round-trip; stats barrier only needs psums).
// Lessons: (r2) fence+same-line atomic across 8192 blocks = 230us serial.
//          (r4) patch_gemm at its 128MB-read floor.
//          (r5) build_M parallelization was the 10us.
//          (r6) uint4 = 8 bf16, NOT 16 — half-row LDS stage caused NaN.
//          (r7) grid.sync() costs ~30us — never worth <30us of traffic.
//          (r8) bf16 img + LDS conv: 39.5us, absmax unchanged.
// ---------------------------------------------------------------------------

typedef __bf16 bf16x8 __attribute__((ext_vector_type(8)));
typedef float f32x4 __attribute__((ext_vector_type(4)));

#define TWO_PI 6.283185307179586f

// workspace layout (bytes)
#define MB_OFF    0u        // __bf16 Mb[16*256]        (8 KB)
#define CB_OFF    8192u     // float cb[16]
#define PSUM_OFF  16384u    // float psum[1024]         (4 KB)
#define PSQ_OFF   20480u    // float psq[1024]          (4 KB)
#define IMG_OFF   24576u    // __bf16 img[8*16*128*128] (4 MB)

// ---------------- kernel 1: build M (bf16) and bias c ----------------------
__global__ __launch_bounds__(256) void build_M(
    const float* __restrict__ Wr, const float* __restrict__ br,
    const float* __restrict__ Wi, const float* __restrict__ bi,
    __bf16* __restrict__ Mb, float* __restrict__ cb) {
  __shared__ float costab[256], sintab[256];
  __shared__ float A2[512];       // interleaved (Ar, Ai)
  __shared__ float part[4][64];
  const int bx = blockIdx.x;
  const int n = bx >> 2;
  const int mq = bx & 3;
  const int t = threadIdx.x;

  float sv, cv;
  sincosf((float)t * (TWO_PI / 256.0f), &sv, &cv);
  costab[t] = cv;
  sintab[t] = sv;
  __syncthreads();

  // phase 1: A[n][k] = (1/16) sum_d (Wr+iWi)[d][k] * e^{+2*pi*i*n*d/16}, k = t
  {
    float ar = 0.f, ai = 0.f;
#pragma unroll
    for (int d = 0; d < 16; ++d) {
      int tt = ((n * d) & 15) * 16;
      float cp = costab[tt], sp = sintab[tt];
      float wr = Wr[d * 256 + t], wi = Wi[d * 256 + t];
      ar += wr * cp - wi * sp;
      ai += wr * sp + wi * cp;
    }
    A2[2 * t]     = ar * (1.0f / 16.0f);
    A2[2 * t + 1] = ai * (1.0f / 16.0f);
  }
  if (mq == 0 && t == 0) {
    float s = 0.f;
    for (int d = 0; d < 16; ++d) {
      int tt = ((n * d) & 15) * 16;
      s += (br[d] - bi[d]) * costab[tt] - (br[d] + bi[d]) * sintab[tt];
    }
    cb[n] = s * (1.0f / 16.0f);
  }
  __syncthreads();

  // phase 2: M[n][m] = sum_k Ar[k]*costab[(k*m)&255] + Ai[k]*sintab[(k*m)&255]
  const int m = mq * 64 + (t & 63);
  const int k0 = (t >> 6) * 64;
  float acc = 0.f;
#pragma unroll 4
  for (int kk = 0; kk < 64; ++kk) {
    const int k = k0 + kk;
    const int idx = (k * m) & 255;
    acc += A2[2 * k] * costab[idx] + A2[2 * k + 1] * sintab[idx];
  }
  part[t >> 6][t & 63] = acc;
  __syncthreads();
  if (t < 64) {
    const float r = part[0][t] + part[1][t] + part[2][t] + part[3][t];
    Mb[n * 256 + mq * 64 + t] = (__bf16)r;
  }
}

// ---------------- kernel 2: patch GEMM via MFMA -> bf16 img ----------------
__global__ __launch_bounds__(256) void patch_gemm(
    const float* __restrict__ x, const __bf16* __restrict__ Mb,
    const float* __restrict__ cb, __bf16* __restrict__ img) {
  const int t = threadIdx.x;
  const int l = t & 63;
  const int wv = t >> 6;
  const int tile = blockIdx.x * 4 + wv;  // 0..8191
  const int b = tile >> 10;              // 0..7
  const int ph = (tile >> 3) & 127;      // patch row
  const int pwb = (tile & 7) * 16;       // patch col base
  const int q = l & 15;                  // A: row d ; B: col patch
  const int g = l >> 4;                  // k-group 0..3

  bf16x8 mfrag[8];
#pragma unroll
  for (int kb = 0; kb < 8; ++kb) {
    mfrag[kb] = *(const bf16x8*)(Mb + q * 256 + kb * 32 + g * 8);
  }
  const float4 cv4 = ((const float4*)cb)[g];
  f32x4 acc = {cv4.x, cv4.y, cv4.z, cv4.w};

  const float* xbase = x + (size_t)b * 4194304 + (size_t)(ph * 16) * 2048 +
                       (size_t)(pwb + q) * 16 + (g & 1) * 8;
#pragma unroll
  for (int kb = 0; kb < 8; ++kb) {
    const int s1 = kb * 2 + (g >> 1);
    const float* xp = xbase + s1 * 2048;
    const float4 v0 = *(const float4*)xp;
    const float4 v1 = *(const float4*)(xp + 4);
    bf16x8 p;
    p[0] = (__bf16)v0.x; p[1] = (__bf16)v0.y; p[2] = (__bf16)v0.z; p[3] = (__bf16)v0.w;
    p[4] = (__bf16)v1.x; p[5] = (__bf16)v1.y; p[6] = (__bf16)v1.z; p[7] = (__bf16)v1.w;
    acc = __builtin_amdgcn_mfma_f32_16x16x32_bf16(mfrag[kb], p, acc, 0, 0, 0);
  }

#pragma unroll
  for (int r = 0; r < 4; ++r) {
    const int d = g * 4 + r;
    img[(((size_t)b * 16 + d) * 128 + ph) * 128 + pwb + q] = (__bf16)acc[r];
  }
}

// ---------------- LDS staging helper (shared by kernels 3 & 4) -------------
// band (+1 halo row each side) -> slds[18][144], 8-col zero pads both sides.
__device__ __forceinline__ void stage_band(
    __bf16 (*slds)[144], const __bf16* __restrict__ img, int p, int row0,
    int t) {
  if (t < 144) {                // 18 rows x 8 chunks of 16 bf16 (2x uint4)
    const int s = t >> 3;
    const int ch = t & 7;
    const int gr = row0 - 1 + s;
    uint4 v0 = {0u, 0u, 0u, 0u}, v1 = {0u, 0u, 0u, 0u};
    if (gr >= 0 && gr <= 127) {
      const uint4* src =
          (const uint4*)(img + (size_t)p * 16384 + gr * 128 + ch * 16);
      v0 = src[0];
      v1 = src[1];
    }
    *(uint4*)&slds[s][8 + ch * 16] = v0;
    *(uint4*)&slds[s][8 + ch * 16 + 8] = v1;
  }
  if (t < 18) {
    uint4 z = {0u, 0u, 0u, 0u};
    *(uint4*)&slds[t][0] = z;
    *(uint4*)&slds[t][136] = z;
  }
}

// ---------------- kernel 3: conv stats only --------------------------------
// grid 1024: bx -> plane p = bx>>3 (b = p>>4, d = p&15), band = bx&7 (16 rows)
// thread t: col j = t&127, rows h*8..h*8+7 (consecutive -> LDS-read CSE).
__global__ __launch_bounds__(256) void conv_stats(
    const __bf16* __restrict__ img, const float* __restrict__ cw,
    const float* __restrict__ cbias, float* __restrict__ psum,
    float* __restrict__ psq) {
  __shared__ alignas(16) __bf16 slds[18][144];
  __shared__ float r1[4], r2[4];

  const int bx = blockIdx.x;
  const int p = bx >> 3;
  const int d = p & 15;
  const int t = threadIdx.x;
  const int row0 = (bx & 7) * 16;

  stage_band(slds, img, p, row0, t);
  __syncthreads();

  float w[9];
#pragma unroll
  for (int q = 0; q < 9; ++q) w[q] = cw[d * 9 + q];
  const float bias = cbias[d];
  const int j = t & 127;
  const int h = t >> 7;         // 0: rows 0-7, 1: rows 8-15

  float s1 = 0.f, s2 = 0.f;
#pragma unroll
  for (int k = 0; k < 8; ++k) {
    const int r = h * 8 + k;    // local row; lds rows r..r+2
    float acc = bias;
#pragma unroll
    for (int u = 0; u < 3; ++u) {
#pragma unroll
      for (int v = 0; v < 3; ++v) {
        acc += w[u * 3 + v] * (float)slds[r + u][7 + j + v];
      }
    }
    s1 += acc;
    s2 += acc * acc;
  }

#pragma unroll
  for (int off = 32; off > 0; off >>= 1) {
    s1 += __shfl_down(s1, off, 64);
    s2 += __shfl_down(s2, off, 64);
  }
  if ((t & 63) == 0) { r1[t >> 6] = s1; r2[t >> 6] = s2; }
  __syncthreads();
  if (t == 0) {
    psum[bx] = r1[0] + r1[1] + r1[2] + r1[3];
    psq[bx]  = r2[0] + r2[1] + r2[2] + r2[3];
  }
}

// ---------------- kernel 4: finalize + conv recompute + normalize + write --
// grid 1024, same mapping. t<64 reduces channel-d partials while others
// stage LDS; single __syncthreads covers both; then conv -> out directly.
__global__ __launch_bounds__(256) void conv_norm(
    const __bf16* __restrict__ img, const float* __restrict__ cw,
    const float* __restrict__ cbias, const float* __restrict__ psum,
    const float* __restrict__ psq, const float* __restrict__ gamma,
    const float* __restrict__ beta, float* __restrict__ out) {
  __shared__ alignas(16) __bf16 slds[18][144];
  __shared__ float sc_sh, sh_sh;

  const int bx = blockIdx.x;
  const int p = bx >> 3;
  const int d = p & 15;
  const int t = threadIdx.x;
  const int row0 = (bx & 7) * 16;

  stage_band(slds, img, p, row0, t);

  if (t < 64) {                 // 64 partials for channel d: psum[b*128+d*8+band]
    const int bb = t >> 3;
    const int bd = t & 7;
    float a1 = psum[bb * 128 + d * 8 + bd];
    float a2 = psq [bb * 128 + d * 8 + bd];
#pragma unroll
    for (int off = 32; off > 0; off >>= 1) {
      a1 += __shfl_down(a1, off, 64);
      a2 += __shfl_down(a2, off, 64);
    }
    if (t == 0) {
      const float invN = 1.0f / 131072.0f;
      const float mean = a1 * invN;
      const float var = a2 * invN - mean * mean;
      const float sc = gamma[d] * rsqrtf(var + 1e-5f);
      sc_sh = sc;
      sh_sh = beta[d] - mean * sc;
    }
  }
  __syncthreads();

  float w[9];
#pragma unroll
  for (int q = 0; q < 9; ++q) w[q] = cw[d * 9 + q];
  const float bias = cbias[d];
  const float sc = sc_sh, sh = sh_sh;
  const int j = t & 127;
  const int h = t >> 7;

#pragma unroll
  for (int k = 0; k < 8; ++k) {
    const int r = h * 8 + k;
    float acc = bias;
#pragma unroll
    for (int u = 0; u < 3; ++u) {
#pragma unroll
      for (int v = 0; v < 3; ++v) {
        acc += w[u * 3 + v] * (float)slds[r + u][7 + j + v];
      }
    }
    out[(size_t)p * 16384 + (row0 + r) * 128 + j] = acc * sc + sh;
  }
}

// ---------------- launcher --------------------------------------------------
extern "C" void kernel_launch(void* const* d_in, const int* in_sizes, int n_in,
                              void* d_out, int out_size, void* d_ws,
                              size_t ws_size, hipStream_t stream) {
  const float* x     = (const float*)d_in[0];
  const float* Wr    = (const float*)d_in[1];
  const float* br    = (const float*)d_in[2];
  const float* Wi    = (const float*)d_in[3];
  const float* bi    = (const float*)d_in[4];
  const float* cw    = (const float*)d_in[5];
  const float* cbias = (const float*)d_in[6];
  const float* gamma = (const float*)d_in[7];
  const float* beta  = (const float*)d_in[8];
  float* out = (float*)d_out;

  char* w = (char*)d_ws;
  __bf16* Mb   = (__bf16*)(w + MB_OFF);
  float* cb    = (float*)(w + CB_OFF);
  float* psum  = (float*)(w + PSUM_OFF);
  float* psq   = (float*)(w + PSQ_OFF);
  __bf16* img  = (__bf16*)(w + IMG_OFF);

  build_M<<<64, 256, 0, stream>>>(Wr, br, Wi, bi, Mb, cb);
  patch_gemm<<<2048, 256, 0, stream>>>(x, Mb, cb, img);
  conv_stats<<<1024, 256, 0, stream>>>(img, cw, cbias, psum, psq);
  conv_norm<<<1024, 256, 0, stream>>>(img, cw, cbias, psum, psq, gamma, beta,
                                      out);
}